// Round 2
// baseline (2338.147 us; speedup 1.0000x reference)
//
#include <hip/hip_runtime.h>

constexpr int B_ = 8;
constexpr int N_ = 4096;
constexpr int BN_ = B_ * N_;
constexpr float BN_EPS = 1e-5f;

// ---------------- prep0: (B,3,N) -> (B*N,4) rows [x,y,z, -0.5*|x|^2] ----------------
__global__ void prep0_kernel(const float* __restrict__ x, float* __restrict__ xa0) {
  int i = blockIdx.x * 256 + threadIdx.x;
  int b = i >> 12, n = i & (N_ - 1);
  const float* xb = x + (size_t)b * 3 * N_;
  float x0 = xb[n], x1 = xb[N_ + n], x2 = xb[2 * N_ + n];
  float4 v = make_float4(x0, x1, x2, -0.5f * (x0 * x0 + x1 * x1 + x2 * x2));
  *reinterpret_cast<float4*>(xa0 + (size_t)i * 4) = v;
}

__device__ __forceinline__ float min16f(const float tv[16]) {
  float m0 = fminf(tv[0], tv[1]),   m1 = fminf(tv[2], tv[3]);
  float m2 = fminf(tv[4], tv[5]),   m3 = fminf(tv[6], tv[7]);
  float m4 = fminf(tv[8], tv[9]),   m5 = fminf(tv[10], tv[11]);
  float m6 = fminf(tv[12], tv[13]), m7 = fminf(tv[14], tv[15]);
  return fminf(fminf(fminf(m0, m1), fminf(m2, m3)), fminf(fminf(m4, m5), fminf(m6, m7)));
}

// register-resident top-16 replacement: slot id lives in the 4 low mantissa bits of
// the value, so all 16 packed values are distinct and "find the min entry" is an
// exact equality match; replacement = 16 unrolled compare-selects (no LDS, no scratch).
__device__ __forceinline__ void replace16(float tv[16], int ti[16], float d, int idx,
                                          float& curmin) {
  unsigned mp = __float_as_uint(curmin);
  unsigned s = mp & 15u;
  float dp = __uint_as_float((__float_as_uint(d) & ~15u) | s);
#pragma unroll
  for (int k = 0; k < 16; ++k) {
    bool hit = (__float_as_uint(tv[k]) == mp);
    tv[k] = hit ? dp : tv[k];
    ti[k] = hit ? idx : ti[k];
  }
  curmin = min16f(tv);
}

// ---------------- knn: 2 rows per thread scan one 1024-candidate chunk ----------------
// key(m) = dot(x_n, x_m) - 0.5*|x_m|^2 (monotone-equivalent to reference pd ranking;
// the -0.5|x_m|^2 term is folded in as an augmented feature column with rf[AUGC]=1).
// Candidate tile staged in LDS, read as wave-uniform broadcast ds_read_b128; each
// broadcast feeds BOTH rows' FMA chains (2 independent chains also cover FMA latency).
template<int CQ>  // feature float4-quads per row: 1 (stride 4) or 9 (stride 36)
__global__ __launch_bounds__(256) void knn_kernel(const float* __restrict__ xa,
                                                  float2* __restrict__ cand16) {
  constexpr int STR = CQ * 4;
  constexpr int TILE = 128;
  constexpr int CHUNK = 1024;
  constexpr int NT = CHUNK / TILE;
  constexpr int TILE_F = TILE * STR;
  constexpr int NPRE = (TILE_F / 4 + 255) / 256;
  __shared__ float tile[2][TILE_F];

  const int b = blockIdx.y;
  const int chunk = blockIdx.x & 3;
  const int rg = blockIdx.x >> 2;                 // 8 row-groups of 512 rows
  const int row0 = rg * 512 + threadIdx.x;
  const int row1 = row0 + 256;
  const float* base = xa + (size_t)b * N_ * STR;

  float rf0[STR], rf1[STR];
#pragma unroll
  for (int q = 0; q < CQ; ++q) {
    float4 v0 = *reinterpret_cast<const float4*>(base + (size_t)row0 * STR + 4 * q);
    float4 v1 = *reinterpret_cast<const float4*>(base + (size_t)row1 * STR + 4 * q);
    rf0[4 * q] = v0.x; rf0[4 * q + 1] = v0.y; rf0[4 * q + 2] = v0.z; rf0[4 * q + 3] = v0.w;
    rf1[4 * q] = v1.x; rf1[4 * q + 1] = v1.y; rf1[4 * q + 2] = v1.z; rf1[4 * q + 3] = v1.w;
  }
  constexpr int AUGC = (CQ == 1) ? 3 : 32;
  rf0[AUGC] = 1.0f; rf1[AUGC] = 1.0f;             // multiplies candidate's -0.5*|x_m|^2
#pragma unroll
  for (int c = AUGC + 1; c < STR; ++c) { rf0[c] = 0.0f; rf1[c] = 0.0f; }

  float tv0[16], tv1[16]; int ti0[16], ti1[16];
#pragma unroll
  for (int i = 0; i < 16; ++i) {
    float init = __uint_as_float((__float_as_uint(-3.0e38f) & ~15u) | (unsigned)i);
    tv0[i] = init; tv1[i] = init; ti0[i] = 0; ti1[i] = 0;
  }
  float curmin0 = min16f(tv0), curmin1 = min16f(tv1);

  const int m0 = chunk * CHUNK;

  // stage tile 0
  {
    const float4* src = reinterpret_cast<const float4*>(base + (size_t)m0 * STR);
    float4* dst = reinterpret_cast<float4*>(tile[0]);
    for (int f = threadIdx.x; f < TILE_F / 4; f += 256) dst[f] = src[f];
  }
  __syncthreads();

  for (int t = 0; t < NT; ++t) {
    const int cur = t & 1;
    float4 pre[NPRE];
    const bool hasNext = (t + 1 < NT);
    if (hasNext) {  // issue next-tile loads early (hide HBM/L2 latency under compute)
      const float4* src = reinterpret_cast<const float4*>(base + (size_t)(m0 + (t + 1) * TILE) * STR);
#pragma unroll
      for (int k = 0; k < NPRE; ++k) {
        int f = threadIdx.x + k * 256;
        if (f < TILE_F / 4) pre[k] = src[f];
      }
    }
    const float* tl = tile[cur];
    for (int mb = 0; mb < TILE; mb += 8) {
      float d0[8], d1[8];
#pragma unroll
      for (int q8 = 0; q8 < 8; ++q8) {
        const float4* cf = reinterpret_cast<const float4*>(tl + (mb + q8) * STR);
        float a0 = 0.0f, a1 = 0.0f;
#pragma unroll
        for (int q = 0; q < CQ; ++q) {
          float4 v = cf[q];                       // uniform address -> broadcast ds_read
          a0 = fmaf(rf0[4 * q], v.x, a0);
          a1 = fmaf(rf1[4 * q], v.x, a1);
          a0 = fmaf(rf0[4 * q + 1], v.y, a0);
          a1 = fmaf(rf1[4 * q + 1], v.y, a1);
          a0 = fmaf(rf0[4 * q + 2], v.z, a0);
          a1 = fmaf(rf1[4 * q + 2], v.z, a1);
          a0 = fmaf(rf0[4 * q + 3], v.w, a0);
          a1 = fmaf(rf1[4 * q + 3], v.w, a1);
        }
        d0[q8] = a0; d1[q8] = a1;
      }
      float mx0 = d0[0], mx1 = d1[0];
#pragma unroll
      for (int q8 = 1; q8 < 8; ++q8) { mx0 = fmaxf(mx0, d0[q8]); mx1 = fmaxf(mx1, d1[q8]); }
      const int mbase = m0 + t * TILE + mb;
      if (mx0 > curmin0) {
#pragma unroll
        for (int q8 = 0; q8 < 8; ++q8)
          if (d0[q8] > curmin0) replace16(tv0, ti0, d0[q8], mbase + q8, curmin0);
      }
      if (mx1 > curmin1) {
#pragma unroll
        for (int q8 = 0; q8 < 8; ++q8)
          if (d1[q8] > curmin1) replace16(tv1, ti1, d1[q8], mbase + q8, curmin1);
      }
    }
    if (hasNext) {
      float4* dst = reinterpret_cast<float4*>(tile[cur ^ 1]);
#pragma unroll
      for (int k = 0; k < NPRE; ++k) {
        int f = threadIdx.x + k * 256;
        if (f < TILE_F / 4) dst[f] = pre[k];
      }
    }
    __syncthreads();
  }

  float2* outp0 = cand16 + ((size_t)(chunk * B_ + b) * N_ + row0) * 16;
  float2* outp1 = cand16 + ((size_t)(chunk * B_ + b) * N_ + row1) * 16;
#pragma unroll
  for (int i = 0; i < 16; ++i) {
    outp0[i] = make_float2(tv0[i], __int_as_float(ti0[i]));
    outp1[i] = make_float2(tv1[i], __int_as_float(ti1[i]));
  }
}

// ---------------- merge 4 chunk-wise top-16 lists -> final idx ----------------
__global__ void knn_merge_kernel(const float2* __restrict__ cand16, int* __restrict__ idx_out) {
  const int i = blockIdx.x * 256 + threadIdx.x;  // row over B*N
  float tv[16]; int ti[16];
  const float2* c0 = cand16 + (size_t)i * 16;
#pragma unroll
  for (int k = 0; k < 16; ++k) { float2 pr = c0[k]; tv[k] = pr.x; ti[k] = __float_as_int(pr.y); }
  float curmin = min16f(tv);
  for (int c = 1; c < 4; ++c) {
    const float2* cc = cand16 + ((size_t)c * BN_ + i) * 16;
#pragma unroll
    for (int k = 0; k < 16; ++k) {
      float2 pr = cc[k];
      if (pr.x > curmin) replace16(tv, ti, pr.x, __float_as_int(pr.y), curmin);
    }
  }
  int4* op = reinterpret_cast<int4*>(idx_out + (size_t)i * 16);
  op[0] = make_int4(ti[0], ti[1], ti[2], ti[3]);
  op[1] = make_int4(ti[4], ti[5], ti[6], ti[7]);
  op[2] = make_int4(ti[8], ti[9], ti[10], ti[11]);
  op[3] = make_int4(ti[12], ti[13], ti[14], ti[15]);
}

// ---------------- edge conv: y = W.[center; nb-center]; emit ymax/ymin + BN partials ----
template<int CIN, int O, int ASTR>
__global__ __launch_bounds__(256) void conv_kernel(const float* __restrict__ xa,
                                                   const int* __restrict__ idxg,
                                                   const float* __restrict__ W,
                                                   float* __restrict__ ymax, float* __restrict__ ymin,
                                                   float* __restrict__ partial) {
  constexpr int PPB = 32;                  // points per block
  constexpr int JPL = (O == 64) ? 16 : 8;  // neighbors per lane
  __shared__ float Wt[2 * CIN * O];        // transposed: Wt[c*O+o]
  __shared__ float dbuf[4][CIN * 16];      // per-wave diff tile d[c][j]
  __shared__ float ls1[O], ls2[O];

  const int tid = threadIdx.x;
  const int lane = tid & 63;
  const int wv = tid >> 6;

  for (int i = tid; i < 2 * CIN * O; i += 256) {
    int c = i / O, o2 = i % O;
    Wt[i] = W[o2 * (2 * CIN) + c];
  }
  if (tid < O) { ls1[tid] = 0.f; ls2[tid] = 0.f; }
  __syncthreads();

  const int o = lane % O;
  const int jh = lane / O;
  const int j0 = jh * JPL;
  const int j = lane & 15;
  const int cg = lane >> 4;

  float wreg[CIN];  // diff-part weights, per-lane column
#pragma unroll
  for (int c = 0; c < CIN; ++c) wreg[c] = Wt[(CIN + c) * O + o];

  float s1 = 0.f, s2 = 0.f;
  float* dw = dbuf[wv];

  const int pbase = blockIdx.x * PPB + wv * (PPB / 4);
  for (int p = pbase; p < pbase + PPB / 4; ++p) {
    const int b = p >> 12;
    const float* cp = xa + (size_t)p * ASTR;
    float cf[CIN];
    if constexpr (CIN == 3) {
      float4 v = *reinterpret_cast<const float4*>(cp);
      cf[0] = v.x; cf[1] = v.y; cf[2] = v.z;
    } else {
#pragma unroll
      for (int q = 0; q < CIN / 4; ++q) {
        float4 v = *reinterpret_cast<const float4*>(cp + 4 * q);
        cf[4 * q] = v.x; cf[4 * q + 1] = v.y; cf[4 * q + 2] = v.z; cf[4 * q + 3] = v.w;
      }
    }
    const int idxj = idxg[(size_t)p * 16 + j];
    const float* np = xa + (size_t)(b * N_ + idxj) * ASTR;
    if constexpr (CIN == 3) {
      if (cg == 0) {
        float4 nv = *reinterpret_cast<const float4*>(np);
        dw[0 * 16 + j] = nv.x - cf[0];
        dw[1 * 16 + j] = nv.y - cf[1];
        dw[2 * 16 + j] = nv.z - cf[2];
      }
    } else {
      float4 na = *reinterpret_cast<const float4*>(np + cg * 8);
      float4 nb2 = *reinterpret_cast<const float4*>(np + cg * 8 + 4);
      float4 ca = *reinterpret_cast<const float4*>(cp + cg * 8);
      float4 cb = *reinterpret_cast<const float4*>(cp + cg * 8 + 4);
      dw[(cg * 8 + 0) * 16 + j] = na.x - ca.x;
      dw[(cg * 8 + 1) * 16 + j] = na.y - ca.y;
      dw[(cg * 8 + 2) * 16 + j] = na.z - ca.z;
      dw[(cg * 8 + 3) * 16 + j] = na.w - ca.w;
      dw[(cg * 8 + 4) * 16 + j] = nb2.x - cb.x;
      dw[(cg * 8 + 5) * 16 + j] = nb2.y - cb.y;
      dw[(cg * 8 + 6) * 16 + j] = nb2.z - cb.z;
      dw[(cg * 8 + 7) * 16 + j] = nb2.w - cb.w;
    }
    // center part (k-independent)
    float y0 = 0.f;
#pragma unroll
    for (int c = 0; c < CIN; ++c) y0 = fmaf(Wt[c * O + o], cf[c], y0);
    float y[JPL];
#pragma unroll
    for (int jj = 0; jj < JPL; ++jj) y[jj] = y0;
#pragma unroll
    for (int c = 0; c < CIN; ++c) {
      float w = wreg[c];
#pragma unroll
      for (int jq = 0; jq < JPL / 4; ++jq) {
        float4 d4 = *reinterpret_cast<const float4*>(dw + c * 16 + j0 + 4 * jq);
        y[4 * jq + 0] = fmaf(w, d4.x, y[4 * jq + 0]);
        y[4 * jq + 1] = fmaf(w, d4.y, y[4 * jq + 1]);
        y[4 * jq + 2] = fmaf(w, d4.z, y[4 * jq + 2]);
        y[4 * jq + 3] = fmaf(w, d4.w, y[4 * jq + 3]);
      }
    }
    float mx = y[0], mn = y[0];
#pragma unroll
    for (int jj = 0; jj < JPL; ++jj) {
      s1 += y[jj];
      s2 = fmaf(y[jj], y[jj], s2);
      if (jj) { mx = fmaxf(mx, y[jj]); mn = fminf(mn, y[jj]); }
    }
    if constexpr (O == 32) {
      mx = fmaxf(mx, __shfl_xor(mx, 32));
      mn = fminf(mn, __shfl_xor(mn, 32));
    }
    ymax[(size_t)p * O + o] = mx;
    ymin[(size_t)p * O + o] = mn;
  }
  atomicAdd(&ls1[o], s1);
  atomicAdd(&ls2[o], s2);
  __syncthreads();
  if (tid < O) {
    partial[(size_t)blockIdx.x * (2 * O) + tid] = ls1[tid];
    partial[(size_t)blockIdx.x * (2 * O) + O + tid] = ls2[tid];
  }
}

// ---------------- BN stats -> per-channel affine (a, b) ----------------
template<int O>
__global__ void bnprep_kernel(const float* __restrict__ partial,
                              const float* __restrict__ gamma, const float* __restrict__ beta,
                              float* __restrict__ ab) {
  __shared__ float r1[256], r2[256];
  const int o = blockIdx.x;
  float a1 = 0.f, a2 = 0.f;
  for (int i = threadIdx.x; i < 1024; i += 256) {
    a1 += partial[(size_t)i * (2 * O) + o];
    a2 += partial[(size_t)i * (2 * O) + O + o];
  }
  r1[threadIdx.x] = a1; r2[threadIdx.x] = a2;
  __syncthreads();
  for (int s = 128; s > 0; s >>= 1) {
    if (threadIdx.x < s) { r1[threadIdx.x] += r1[threadIdx.x + s]; r2[threadIdx.x] += r2[threadIdx.x + s]; }
    __syncthreads();
  }
  if (threadIdx.x == 0) {
    const double cnt = (double)BN_ * 16.0;
    double mean = (double)r1[0] / cnt;
    double var = (double)r2[0] / cnt - mean * mean;
    double a = (double)gamma[o] / sqrt(var + (double)BN_EPS);
    ab[o] = (float)a;
    ab[64 + o] = (float)((double)beta[o] - mean * a);
  }
}

// ---------------- finalize: relu(a*(a>0?ymax:ymin)+b), write next xa + global max ----
template<int O, bool WRITE_XA, int GOFF>
__global__ __launch_bounds__(256) void finalize_kernel(const float* __restrict__ ymax,
                                                       const float* __restrict__ ymin,
                                                       const float* __restrict__ ab,
                                                       float* __restrict__ xa_out,
                                                       float* __restrict__ gmax) {
  __shared__ float la[O], lb[O];
  __shared__ unsigned lgm[O];
  const int tid = threadIdx.x;
  if (tid < O) { la[tid] = ab[tid]; lb[tid] = ab[64 + tid]; lgm[tid] = 0u; }
  __syncthreads();
  const int p = blockIdx.x * 256 + tid;
  const int b = p >> 12;
  float sq = 0.f;
#pragma unroll
  for (int q = 0; q < O / 4; ++q) {
    float4 mx = *reinterpret_cast<const float4*>(ymax + (size_t)p * O + 4 * q);
    float4 mn = *reinterpret_cast<const float4*>(ymin + (size_t)p * O + 4 * q);
    float r0, r1, r2, r3;
    { float a = la[4*q+0], c = lb[4*q+0]; r0 = fmaxf(fmaf(a, (a > 0.f ? mx.x : mn.x), c), 0.f); }
    { float a = la[4*q+1], c = lb[4*q+1]; r1 = fmaxf(fmaf(a, (a > 0.f ? mx.y : mn.y), c), 0.f); }
    { float a = la[4*q+2], c = lb[4*q+2]; r2 = fmaxf(fmaf(a, (a > 0.f ? mx.z : mn.z), c), 0.f); }
    { float a = la[4*q+3], c = lb[4*q+3]; r3 = fmaxf(fmaf(a, (a > 0.f ? mx.w : mn.w), c), 0.f); }
    sq = fmaf(r0, r0, sq); sq = fmaf(r1, r1, sq); sq = fmaf(r2, r2, sq); sq = fmaf(r3, r3, sq);
    atomicMax(&lgm[4*q+0], __float_as_uint(r0));
    atomicMax(&lgm[4*q+1], __float_as_uint(r1));
    atomicMax(&lgm[4*q+2], __float_as_uint(r2));
    atomicMax(&lgm[4*q+3], __float_as_uint(r3));
    if constexpr (WRITE_XA)
      *reinterpret_cast<float4*>(xa_out + (size_t)p * 36 + 4 * q) = make_float4(r0, r1, r2, r3);
  }
  if constexpr (WRITE_XA) {
    xa_out[(size_t)p * 36 + 32] = -0.5f * sq;
    xa_out[(size_t)p * 36 + 33] = 0.f;
    xa_out[(size_t)p * 36 + 34] = 0.f;
    xa_out[(size_t)p * 36 + 35] = 0.f;
  }
  __syncthreads();
  if (tid < O)
    atomicMax(reinterpret_cast<unsigned*>(gmax) + b * 128 + GOFF + tid, lgm[tid]);
}

// ---------------- fc: (8,128) @ (64,128)^T + bfc -> (8,64) ----------------
__global__ void fc_kernel(const float* __restrict__ gmax, const float* __restrict__ Wfc,
                          const float* __restrict__ bfc, float* __restrict__ outp) {
  const int t = blockIdx.x * 256 + threadIdx.x;  // 0..511
  const int b = t >> 6, o = t & 63;
  float acc = bfc[o];
  const float* g = gmax + b * 128;
  const float* w = Wfc + o * 128;
#pragma unroll
  for (int c = 0; c < 128; ++c) acc = fmaf(g[c], w[c], acc);
  outp[(size_t)b * 64 + o] = acc;
}

extern "C" void kernel_launch(void* const* d_in, const int* in_sizes, int n_in,
                              void* d_out, int out_size, void* d_ws, size_t ws_size,
                              hipStream_t stream) {
  (void)in_sizes; (void)n_in; (void)out_size; (void)ws_size;
  const float* x   = (const float*)d_in[0];
  const float* W1  = (const float*)d_in[1];
  const float* g1  = (const float*)d_in[2];
  const float* b1  = (const float*)d_in[3];
  const float* W2  = (const float*)d_in[4];
  const float* g2  = (const float*)d_in[5];
  const float* b2  = (const float*)d_in[6];
  const float* W3  = (const float*)d_in[7];
  const float* g3  = (const float*)d_in[8];
  const float* b3  = (const float*)d_in[9];
  const float* Wfc = (const float*)d_in[10];
  const float* bfc = (const float*)d_in[11];
  float* outp = (float*)d_out;

  char* ws = (char*)d_ws;
  size_t off = 0;
  auto alloc = [&](size_t bytes) { char* p = ws + off; off += (bytes + 511) & ~(size_t)511; return p; };
  float* gmax    = (float*)alloc((size_t)B_ * 128 * 4);
  float* ab      = (float*)alloc(128 * 4);
  float* partial = (float*)alloc((size_t)1024 * 128 * 4);
  float* xa0     = (float*)alloc((size_t)BN_ * 4 * 4);
  float* xa1     = (float*)alloc((size_t)BN_ * 36 * 4);
  float* xa2     = (float*)alloc((size_t)BN_ * 36 * 4);
  int*   idxb    = (int*)  alloc((size_t)BN_ * 16 * 4);
  float* ymax    = (float*)alloc((size_t)BN_ * 64 * 4);
  float* ymin    = (float*)alloc((size_t)BN_ * 64 * 4);
  float2* cand16 = (float2*)ymax;  // alias: knn scratch lives where ymax/ymin will go

  hipMemsetAsync(gmax, 0, (size_t)B_ * 128 * 4, stream);

  dim3 blk(256);
  prep0_kernel<<<BN_ / 256, blk, 0, stream>>>(x, xa0);

  // layer 1 (C=3 -> 32)
  knn_kernel<1><<<dim3(32, 8), blk, 0, stream>>>(xa0, cand16);
  knn_merge_kernel<<<BN_ / 256, blk, 0, stream>>>(cand16, idxb);
  conv_kernel<3, 32, 4><<<BN_ / 32, blk, 0, stream>>>(xa0, idxb, W1, ymax, ymin, partial);
  bnprep_kernel<32><<<32, blk, 0, stream>>>(partial, g1, b1, ab);
  finalize_kernel<32, true, 0><<<BN_ / 256, blk, 0, stream>>>(ymax, ymin, ab, xa1, gmax);

  // layer 2 (32 -> 32)
  knn_kernel<9><<<dim3(32, 8), blk, 0, stream>>>(xa1, cand16);
  knn_merge_kernel<<<BN_ / 256, blk, 0, stream>>>(cand16, idxb);
  conv_kernel<32, 32, 36><<<BN_ / 32, blk, 0, stream>>>(xa1, idxb, W2, ymax, ymin, partial);
  bnprep_kernel<32><<<32, blk, 0, stream>>>(partial, g2, b2, ab);
  finalize_kernel<32, true, 32><<<BN_ / 256, blk, 0, stream>>>(ymax, ymin, ab, xa2, gmax);

  // layer 3 (32 -> 64)
  knn_kernel<9><<<dim3(32, 8), blk, 0, stream>>>(xa2, cand16);
  knn_merge_kernel<<<BN_ / 256, blk, 0, stream>>>(cand16, idxb);
  conv_kernel<32, 64, 36><<<BN_ / 32, blk, 0, stream>>>(xa2, idxb, W3, ymax, ymin, partial);
  bnprep_kernel<64><<<64, blk, 0, stream>>>(partial, g3, b3, ab);
  finalize_kernel<64, false, 64><<<BN_ / 256, blk, 0, stream>>>(ymax, ymin, ab, nullptr, gmax);

  fc_kernel<<<2, blk, 0, stream>>>(gmax, Wfc, bfc, outp);
}

// Round 3
// 2243.251 us; speedup vs baseline: 1.0423x; 1.0423x over previous
//
#include <hip/hip_runtime.h>

constexpr int B_ = 8;
constexpr int N_ = 4096;
constexpr int BN_ = B_ * N_;
constexpr float BN_EPS = 1e-5f;
constexpr int NCH_ = 8;   // knn candidate chunks (grid-occupancy lever: 512 blocks = 2/CU)

// ---------------- prep0: (B,3,N) -> (B*N,4) rows [x,y,z, -0.5*|x|^2] ----------------
__global__ void prep0_kernel(const float* __restrict__ x, float* __restrict__ xa0) {
  int i = blockIdx.x * 256 + threadIdx.x;
  int b = i >> 12, n = i & (N_ - 1);
  const float* xb = x + (size_t)b * 3 * N_;
  float x0 = xb[n], x1 = xb[N_ + n], x2 = xb[2 * N_ + n];
  float4 v = make_float4(x0, x1, x2, -0.5f * (x0 * x0 + x1 * x1 + x2 * x2));
  *reinterpret_cast<float4*>(xa0 + (size_t)i * 4) = v;
}

__device__ __forceinline__ float min16f(const float tv[16]) {
  float m0 = fminf(tv[0], tv[1]),   m1 = fminf(tv[2], tv[3]);
  float m2 = fminf(tv[4], tv[5]),   m3 = fminf(tv[6], tv[7]);
  float m4 = fminf(tv[8], tv[9]),   m5 = fminf(tv[10], tv[11]);
  float m6 = fminf(tv[12], tv[13]), m7 = fminf(tv[14], tv[15]);
  return fminf(fminf(fminf(m0, m1), fminf(m2, m3)), fminf(fminf(m4, m5), fminf(m6, m7)));
}

// register-resident top-16 replacement: slot id lives in the 4 low mantissa bits of
// the value, so all 16 packed values are distinct and "find the min entry" is an
// exact equality match; replacement = 16 unrolled compare-selects (no LDS, no scratch).
__device__ __forceinline__ void replace16(float tv[16], int ti[16], float d, int idx,
                                          float& curmin) {
  unsigned mp = __float_as_uint(curmin);
  unsigned s = mp & 15u;
  float dp = __uint_as_float((__float_as_uint(d) & ~15u) | s);
#pragma unroll
  for (int k = 0; k < 16; ++k) {
    bool hit = (__float_as_uint(tv[k]) == mp);
    tv[k] = hit ? dp : tv[k];
    ti[k] = hit ? idx : ti[k];
  }
  curmin = min16f(tv);
}

// ---------------- knn: 2 rows per thread scan one 512-candidate chunk ----------------
// key(m) = dot(x_n, x_m) - 0.5*|x_m|^2 (monotone-equivalent to reference pd ranking;
// acc is INITIALIZED from the candidate's -0.5|x_m|^2 column, so only NF FMAs/row).
// Candidate tile staged in LDS, read as wave-uniform broadcast ds_read; each
// broadcast feeds BOTH rows' FMA chains (2 independent chains cover FMA latency).
template<int CQ>  // feature float4-quads per row: 1 (stride 4) or 9 (stride 36)
__global__ __launch_bounds__(256) void knn_kernel(const float* __restrict__ xa,
                                                  float2* __restrict__ cand16) {
  constexpr int STR = CQ * 4;
  constexpr int NF = (CQ == 1) ? 3 : 32;   // real features; augmented col at NF
  constexpr int TILE = 128;
  constexpr int CHUNK = 4096 / NCH_;
  constexpr int NT = CHUNK / TILE;
  constexpr int TILE_F = TILE * STR;
  constexpr int NPRE = (TILE_F / 4 + 255) / 256;
  __shared__ float tile[2][TILE_F];

  const int b = blockIdx.y;
  const int chunk = blockIdx.x & (NCH_ - 1);
  const int rg = blockIdx.x / NCH_;               // row-groups of 512 rows
  const int row0 = rg * 512 + threadIdx.x;
  const int row1 = row0 + 256;
  const float* base = xa + (size_t)b * N_ * STR;

  float rf0[NF], rf1[NF];
  if constexpr (CQ == 1) {
    float4 v0 = *reinterpret_cast<const float4*>(base + (size_t)row0 * STR);
    float4 v1 = *reinterpret_cast<const float4*>(base + (size_t)row1 * STR);
    rf0[0] = v0.x; rf0[1] = v0.y; rf0[2] = v0.z;
    rf1[0] = v1.x; rf1[1] = v1.y; rf1[2] = v1.z;
  } else {
#pragma unroll
    for (int q = 0; q < 8; ++q) {
      float4 v0 = *reinterpret_cast<const float4*>(base + (size_t)row0 * STR + 4 * q);
      float4 v1 = *reinterpret_cast<const float4*>(base + (size_t)row1 * STR + 4 * q);
      rf0[4 * q] = v0.x; rf0[4 * q + 1] = v0.y; rf0[4 * q + 2] = v0.z; rf0[4 * q + 3] = v0.w;
      rf1[4 * q] = v1.x; rf1[4 * q + 1] = v1.y; rf1[4 * q + 2] = v1.z; rf1[4 * q + 3] = v1.w;
    }
  }

  float tv0[16], tv1[16]; int ti0[16], ti1[16];
#pragma unroll
  for (int i = 0; i < 16; ++i) {
    float init = __uint_as_float((__float_as_uint(-3.0e38f) & ~15u) | (unsigned)i);
    tv0[i] = init; tv1[i] = init; ti0[i] = 0; ti1[i] = 0;
  }
  float curmin0 = min16f(tv0), curmin1 = min16f(tv1);

  const int m0 = chunk * CHUNK;

  // stage tile 0
  {
    const float4* src = reinterpret_cast<const float4*>(base + (size_t)m0 * STR);
    float4* dst = reinterpret_cast<float4*>(tile[0]);
    for (int f = threadIdx.x; f < TILE_F / 4; f += 256) dst[f] = src[f];
  }
  __syncthreads();

  for (int t = 0; t < NT; ++t) {
    const int cur = t & 1;
    float4 pre[NPRE];
    const bool hasNext = (t + 1 < NT);
    if (hasNext) {  // issue next-tile loads early (hide HBM/L2 latency under compute)
      const float4* src = reinterpret_cast<const float4*>(base + (size_t)(m0 + (t + 1) * TILE) * STR);
#pragma unroll
      for (int k = 0; k < NPRE; ++k) {
        int f = threadIdx.x + k * 256;
        if (f < TILE_F / 4) pre[k] = src[f];
      }
    }
    const float* tl = tile[cur];
    for (int mb = 0; mb < TILE; mb += 8) {
      float d0[8], d1[8];
#pragma unroll
      for (int q8 = 0; q8 < 8; ++q8) {
        const float* cf = tl + (mb + q8) * STR;   // uniform address -> broadcast ds_read
        float a0, a1;
        if constexpr (CQ == 1) {
          float4 v = *reinterpret_cast<const float4*>(cf);
          a0 = v.w; a1 = v.w;                     // -0.5*|x_m|^2 column
          a0 = fmaf(rf0[0], v.x, a0);  a1 = fmaf(rf1[0], v.x, a1);
          a0 = fmaf(rf0[1], v.y, a0);  a1 = fmaf(rf1[1], v.y, a1);
          a0 = fmaf(rf0[2], v.z, a0);  a1 = fmaf(rf1[2], v.z, a1);
        } else {
          float aug = cf[32];                     // -0.5*|x_m|^2 column (broadcast b32)
          a0 = aug; a1 = aug;
#pragma unroll
          for (int q = 0; q < 8; ++q) {
            float4 v = reinterpret_cast<const float4*>(cf)[q];
            a0 = fmaf(rf0[4 * q], v.x, a0);
            a1 = fmaf(rf1[4 * q], v.x, a1);
            a0 = fmaf(rf0[4 * q + 1], v.y, a0);
            a1 = fmaf(rf1[4 * q + 1], v.y, a1);
            a0 = fmaf(rf0[4 * q + 2], v.z, a0);
            a1 = fmaf(rf1[4 * q + 2], v.z, a1);
            a0 = fmaf(rf0[4 * q + 3], v.w, a0);
            a1 = fmaf(rf1[4 * q + 3], v.w, a1);
          }
        }
        d0[q8] = a0; d1[q8] = a1;
      }
      float mx0 = d0[0], mx1 = d1[0];
#pragma unroll
      for (int q8 = 1; q8 < 8; ++q8) { mx0 = fmaxf(mx0, d0[q8]); mx1 = fmaxf(mx1, d1[q8]); }
      const int mbase = m0 + t * TILE + mb;
      if (mx0 > curmin0) {
#pragma unroll
        for (int q8 = 0; q8 < 8; ++q8)
          if (d0[q8] > curmin0) replace16(tv0, ti0, d0[q8], mbase + q8, curmin0);
      }
      if (mx1 > curmin1) {
#pragma unroll
        for (int q8 = 0; q8 < 8; ++q8)
          if (d1[q8] > curmin1) replace16(tv1, ti1, d1[q8], mbase + q8, curmin1);
      }
    }
    if (hasNext) {
      float4* dst = reinterpret_cast<float4*>(tile[cur ^ 1]);
#pragma unroll
      for (int k = 0; k < NPRE; ++k) {
        int f = threadIdx.x + k * 256;
        if (f < TILE_F / 4) dst[f] = pre[k];
      }
    }
    __syncthreads();
  }

  float2* outp0 = cand16 + ((size_t)(chunk * B_ + b) * N_ + row0) * 16;
  float2* outp1 = cand16 + ((size_t)(chunk * B_ + b) * N_ + row1) * 16;
#pragma unroll
  for (int i = 0; i < 16; ++i) {
    outp0[i] = make_float2(tv0[i], __int_as_float(ti0[i]));
    outp1[i] = make_float2(tv1[i], __int_as_float(ti1[i]));
  }
}

// ---------------- merge NCH_ chunk-wise top-16 lists -> final idx ----------------
__global__ void knn_merge_kernel(const float2* __restrict__ cand16, int* __restrict__ idx_out) {
  const int i = blockIdx.x * 256 + threadIdx.x;  // row over B*N
  float tv[16]; int ti[16];
  const float2* c0 = cand16 + (size_t)i * 16;
#pragma unroll
  for (int k = 0; k < 16; ++k) { float2 pr = c0[k]; tv[k] = pr.x; ti[k] = __float_as_int(pr.y); }
  float curmin = min16f(tv);
  for (int c = 1; c < NCH_; ++c) {
    const float2* cc = cand16 + ((size_t)c * BN_ + i) * 16;
#pragma unroll
    for (int k = 0; k < 16; ++k) {
      float2 pr = cc[k];
      if (pr.x > curmin) replace16(tv, ti, pr.x, __float_as_int(pr.y), curmin);
    }
  }
  int4* op = reinterpret_cast<int4*>(idx_out + (size_t)i * 16);
  op[0] = make_int4(ti[0], ti[1], ti[2], ti[3]);
  op[1] = make_int4(ti[4], ti[5], ti[6], ti[7]);
  op[2] = make_int4(ti[8], ti[9], ti[10], ti[11]);
  op[3] = make_int4(ti[12], ti[13], ti[14], ti[15]);
}

// ---------------- edge conv: y = W.[center; nb-center]; emit ymax/ymin + BN partials ----
template<int CIN, int O, int ASTR>
__global__ __launch_bounds__(256) void conv_kernel(const float* __restrict__ xa,
                                                   const int* __restrict__ idxg,
                                                   const float* __restrict__ W,
                                                   float* __restrict__ ymax, float* __restrict__ ymin,
                                                   float* __restrict__ partial) {
  constexpr int PPB = 32;                  // points per block
  constexpr int JPL = (O == 64) ? 16 : 8;  // neighbors per lane
  __shared__ float Wt[2 * CIN * O];        // transposed: Wt[c*O+o]
  __shared__ float dbuf[4][CIN * 16];      // per-wave diff tile d[c][j]
  __shared__ float ls1[O], ls2[O];

  const int tid = threadIdx.x;
  const int lane = tid & 63;
  const int wv = tid >> 6;

  for (int i = tid; i < 2 * CIN * O; i += 256) {
    int c = i / O, o2 = i % O;
    Wt[i] = W[o2 * (2 * CIN) + c];
  }
  if (tid < O) { ls1[tid] = 0.f; ls2[tid] = 0.f; }
  __syncthreads();

  const int o = lane % O;
  const int jh = lane / O;
  const int j0 = jh * JPL;
  const int j = lane & 15;
  const int cg = lane >> 4;

  float wreg[CIN];  // diff-part weights, per-lane column
#pragma unroll
  for (int c = 0; c < CIN; ++c) wreg[c] = Wt[(CIN + c) * O + o];

  float s1 = 0.f, s2 = 0.f;
  float* dw = dbuf[wv];

  const int pbase = blockIdx.x * PPB + wv * (PPB / 4);
  for (int p = pbase; p < pbase + PPB / 4; ++p) {
    const int b = p >> 12;
    const float* cp = xa + (size_t)p * ASTR;
    float cf[CIN];
    if constexpr (CIN == 3) {
      float4 v = *reinterpret_cast<const float4*>(cp);
      cf[0] = v.x; cf[1] = v.y; cf[2] = v.z;
    } else {
#pragma unroll
      for (int q = 0; q < CIN / 4; ++q) {
        float4 v = *reinterpret_cast<const float4*>(cp + 4 * q);
        cf[4 * q] = v.x; cf[4 * q + 1] = v.y; cf[4 * q + 2] = v.z; cf[4 * q + 3] = v.w;
      }
    }
    const int idxj = idxg[(size_t)p * 16 + j];
    const float* np = xa + (size_t)(b * N_ + idxj) * ASTR;
    if constexpr (CIN == 3) {
      if (cg == 0) {
        float4 nv = *reinterpret_cast<const float4*>(np);
        dw[0 * 16 + j] = nv.x - cf[0];
        dw[1 * 16 + j] = nv.y - cf[1];
        dw[2 * 16 + j] = nv.z - cf[2];
      }
    } else {
      float4 na = *reinterpret_cast<const float4*>(np + cg * 8);
      float4 nb2 = *reinterpret_cast<const float4*>(np + cg * 8 + 4);
      float4 ca = *reinterpret_cast<const float4*>(cp + cg * 8);
      float4 cb = *reinterpret_cast<const float4*>(cp + cg * 8 + 4);
      dw[(cg * 8 + 0) * 16 + j] = na.x - ca.x;
      dw[(cg * 8 + 1) * 16 + j] = na.y - ca.y;
      dw[(cg * 8 + 2) * 16 + j] = na.z - ca.z;
      dw[(cg * 8 + 3) * 16 + j] = na.w - ca.w;
      dw[(cg * 8 + 4) * 16 + j] = nb2.x - cb.x;
      dw[(cg * 8 + 5) * 16 + j] = nb2.y - cb.y;
      dw[(cg * 8 + 6) * 16 + j] = nb2.z - cb.z;
      dw[(cg * 8 + 7) * 16 + j] = nb2.w - cb.w;
    }
    // center part (k-independent)
    float y0 = 0.f;
#pragma unroll
    for (int c = 0; c < CIN; ++c) y0 = fmaf(Wt[c * O + o], cf[c], y0);
    float y[JPL];
#pragma unroll
    for (int jj = 0; jj < JPL; ++jj) y[jj] = y0;
#pragma unroll
    for (int c = 0; c < CIN; ++c) {
      float w = wreg[c];
#pragma unroll
      for (int jq = 0; jq < JPL / 4; ++jq) {
        float4 d4 = *reinterpret_cast<const float4*>(dw + c * 16 + j0 + 4 * jq);
        y[4 * jq + 0] = fmaf(w, d4.x, y[4 * jq + 0]);
        y[4 * jq + 1] = fmaf(w, d4.y, y[4 * jq + 1]);
        y[4 * jq + 2] = fmaf(w, d4.z, y[4 * jq + 2]);
        y[4 * jq + 3] = fmaf(w, d4.w, y[4 * jq + 3]);
      }
    }
    float mx = y[0], mn = y[0];
#pragma unroll
    for (int jj = 0; jj < JPL; ++jj) {
      s1 += y[jj];
      s2 = fmaf(y[jj], y[jj], s2);
      if (jj) { mx = fmaxf(mx, y[jj]); mn = fminf(mn, y[jj]); }
    }
    if constexpr (O == 32) {
      mx = fmaxf(mx, __shfl_xor(mx, 32));
      mn = fminf(mn, __shfl_xor(mn, 32));
    }
    ymax[(size_t)p * O + o] = mx;
    ymin[(size_t)p * O + o] = mn;
  }
  atomicAdd(&ls1[o], s1);
  atomicAdd(&ls2[o], s2);
  __syncthreads();
  if (tid < O) {
    partial[(size_t)blockIdx.x * (2 * O) + tid] = ls1[tid];
    partial[(size_t)blockIdx.x * (2 * O) + O + tid] = ls2[tid];
  }
}

// ---------------- BN stats -> per-channel affine (a, b) ----------------
template<int O>
__global__ void bnprep_kernel(const float* __restrict__ partial,
                              const float* __restrict__ gamma, const float* __restrict__ beta,
                              float* __restrict__ ab) {
  __shared__ float r1[256], r2[256];
  const int o = blockIdx.x;
  float a1 = 0.f, a2 = 0.f;
  for (int i = threadIdx.x; i < 1024; i += 256) {
    a1 += partial[(size_t)i * (2 * O) + o];
    a2 += partial[(size_t)i * (2 * O) + O + o];
  }
  r1[threadIdx.x] = a1; r2[threadIdx.x] = a2;
  __syncthreads();
  for (int s = 128; s > 0; s >>= 1) {
    if (threadIdx.x < s) { r1[threadIdx.x] += r1[threadIdx.x + s]; r2[threadIdx.x] += r2[threadIdx.x + s]; }
    __syncthreads();
  }
  if (threadIdx.x == 0) {
    const double cnt = (double)BN_ * 16.0;
    double mean = (double)r1[0] / cnt;
    double var = (double)r2[0] / cnt - mean * mean;
    double a = (double)gamma[o] / sqrt(var + (double)BN_EPS);
    ab[o] = (float)a;
    ab[64 + o] = (float)((double)beta[o] - mean * a);
  }
}

// ---------------- finalize: relu(a*(a>0?ymax:ymin)+b), write next xa + global max ----
template<int O, bool WRITE_XA, int GOFF>
__global__ __launch_bounds__(256) void finalize_kernel(const float* __restrict__ ymax,
                                                       const float* __restrict__ ymin,
                                                       const float* __restrict__ ab,
                                                       float* __restrict__ xa_out,
                                                       float* __restrict__ gmax) {
  __shared__ float la[O], lb[O];
  __shared__ unsigned lgm[O];
  const int tid = threadIdx.x;
  if (tid < O) { la[tid] = ab[tid]; lb[tid] = ab[64 + tid]; lgm[tid] = 0u; }
  __syncthreads();
  const int p = blockIdx.x * 256 + tid;
  const int b = p >> 12;
  float sq = 0.f;
#pragma unroll
  for (int q = 0; q < O / 4; ++q) {
    float4 mx = *reinterpret_cast<const float4*>(ymax + (size_t)p * O + 4 * q);
    float4 mn = *reinterpret_cast<const float4*>(ymin + (size_t)p * O + 4 * q);
    float r0, r1, r2, r3;
    { float a = la[4*q+0], c = lb[4*q+0]; r0 = fmaxf(fmaf(a, (a > 0.f ? mx.x : mn.x), c), 0.f); }
    { float a = la[4*q+1], c = lb[4*q+1]; r1 = fmaxf(fmaf(a, (a > 0.f ? mx.y : mn.y), c), 0.f); }
    { float a = la[4*q+2], c = lb[4*q+2]; r2 = fmaxf(fmaf(a, (a > 0.f ? mx.z : mn.z), c), 0.f); }
    { float a = la[4*q+3], c = lb[4*q+3]; r3 = fmaxf(fmaf(a, (a > 0.f ? mx.w : mn.w), c), 0.f); }
    sq = fmaf(r0, r0, sq); sq = fmaf(r1, r1, sq); sq = fmaf(r2, r2, sq); sq = fmaf(r3, r3, sq);
    atomicMax(&lgm[4*q+0], __float_as_uint(r0));
    atomicMax(&lgm[4*q+1], __float_as_uint(r1));
    atomicMax(&lgm[4*q+2], __float_as_uint(r2));
    atomicMax(&lgm[4*q+3], __float_as_uint(r3));
    if constexpr (WRITE_XA)
      *reinterpret_cast<float4*>(xa_out + (size_t)p * 36 + 4 * q) = make_float4(r0, r1, r2, r3);
  }
  if constexpr (WRITE_XA) {
    xa_out[(size_t)p * 36 + 32] = -0.5f * sq;
    xa_out[(size_t)p * 36 + 33] = 0.f;
    xa_out[(size_t)p * 36 + 34] = 0.f;
    xa_out[(size_t)p * 36 + 35] = 0.f;
  }
  __syncthreads();
  if (tid < O)
    atomicMax(reinterpret_cast<unsigned*>(gmax) + b * 128 + GOFF + tid, lgm[tid]);
}

// ---------------- fc: (8,128) @ (64,128)^T + bfc -> (8,64) ----------------
__global__ void fc_kernel(const float* __restrict__ gmax, const float* __restrict__ Wfc,
                          const float* __restrict__ bfc, float* __restrict__ outp) {
  const int t = blockIdx.x * 256 + threadIdx.x;  // 0..511
  const int b = t >> 6, o = t & 63;
  float acc = bfc[o];
  const float* g = gmax + b * 128;
  const float* w = Wfc + o * 128;
#pragma unroll
  for (int c = 0; c < 128; ++c) acc = fmaf(g[c], w[c], acc);
  outp[(size_t)b * 64 + o] = acc;
}

extern "C" void kernel_launch(void* const* d_in, const int* in_sizes, int n_in,
                              void* d_out, int out_size, void* d_ws, size_t ws_size,
                              hipStream_t stream) {
  (void)in_sizes; (void)n_in; (void)out_size; (void)ws_size;
  const float* x   = (const float*)d_in[0];
  const float* W1  = (const float*)d_in[1];
  const float* g1  = (const float*)d_in[2];
  const float* b1  = (const float*)d_in[3];
  const float* W2  = (const float*)d_in[4];
  const float* g2  = (const float*)d_in[5];
  const float* b2  = (const float*)d_in[6];
  const float* W3  = (const float*)d_in[7];
  const float* g3  = (const float*)d_in[8];
  const float* b3  = (const float*)d_in[9];
  const float* Wfc = (const float*)d_in[10];
  const float* bfc = (const float*)d_in[11];
  float* outp = (float*)d_out;

  char* ws = (char*)d_ws;
  size_t off = 0;
  auto alloc = [&](size_t bytes) { char* p = ws + off; off += (bytes + 511) & ~(size_t)511; return p; };
  float* gmax    = (float*)alloc((size_t)B_ * 128 * 4);
  float* ab      = (float*)alloc(128 * 4);
  float* xa0     = (float*)alloc((size_t)BN_ * 4 * 4);
  float* xa1     = (float*)alloc((size_t)BN_ * 36 * 4);
  float* xa2     = (float*)alloc((size_t)BN_ * 36 * 4);
  int*   idxb    = (int*)  alloc((size_t)BN_ * 16 * 4);
  // union region: cand16 (knn+merge phase) aliases {ymax, ymin, partial} (conv phase)
  char*  uni     = alloc((size_t)NCH_ * BN_ * 16 * 8);
  float2* cand16 = (float2*)uni;
  float* ymax    = (float*)uni;
  float* ymin    = (float*)(uni + (size_t)BN_ * 64 * 4);
  float* partial = (float*)(uni + (size_t)BN_ * 64 * 8);

  hipMemsetAsync(gmax, 0, (size_t)B_ * 128 * 4, stream);

  dim3 blk(256);
  prep0_kernel<<<BN_ / 256, blk, 0, stream>>>(x, xa0);

  // layer 1 (C=3 -> 32)
  knn_kernel<1><<<dim3(8 * NCH_, 8), blk, 0, stream>>>(xa0, cand16);
  knn_merge_kernel<<<BN_ / 256, blk, 0, stream>>>(cand16, idxb);
  conv_kernel<3, 32, 4><<<BN_ / 32, blk, 0, stream>>>(xa0, idxb, W1, ymax, ymin, partial);
  bnprep_kernel<32><<<32, blk, 0, stream>>>(partial, g1, b1, ab);
  finalize_kernel<32, true, 0><<<BN_ / 256, blk, 0, stream>>>(ymax, ymin, ab, xa1, gmax);

  // layer 2 (32 -> 32)
  knn_kernel<9><<<dim3(8 * NCH_, 8), blk, 0, stream>>>(xa1, cand16);
  knn_merge_kernel<<<BN_ / 256, blk, 0, stream>>>(cand16, idxb);
  conv_kernel<32, 32, 36><<<BN_ / 32, blk, 0, stream>>>(xa1, idxb, W2, ymax, ymin, partial);
  bnprep_kernel<32><<<32, blk, 0, stream>>>(partial, g2, b2, ab);
  finalize_kernel<32, true, 32><<<BN_ / 256, blk, 0, stream>>>(ymax, ymin, ab, xa2, gmax);

  // layer 3 (32 -> 64)
  knn_kernel<9><<<dim3(8 * NCH_, 8), blk, 0, stream>>>(xa2, cand16);
  knn_merge_kernel<<<BN_ / 256, blk, 0, stream>>>(cand16, idxb);
  conv_kernel<32, 64, 36><<<BN_ / 32, blk, 0, stream>>>(xa2, idxb, W3, ymax, ymin, partial);
  bnprep_kernel<64><<<64, blk, 0, stream>>>(partial, g3, b3, ab);
  finalize_kernel<64, false, 64><<<BN_ / 256, blk, 0, stream>>>(ymax, ymin, ab, nullptr, gmax);

  fc_kernel<<<2, blk, 0, stream>>>(gmax, Wfc, bfc, outp);
}

// Round 6
// 1537.234 us; speedup vs baseline: 1.5210x; 1.4593x over previous
//
#include <hip/hip_runtime.h>

constexpr int B_ = 8;
constexpr int N_ = 4096;
constexpr int BN_ = B_ * N_;
constexpr float BN_EPS = 1e-5f;
constexpr int NCH_ = 8;   // knn candidate chunks

// ---------------- prep0: (B,3,N) -> (B*N,4) rows [x,y,z, -0.5*|x|^2] ----------------
__global__ void prep0_kernel(const float* __restrict__ x, float* __restrict__ xa0) {
  int i = blockIdx.x * 256 + threadIdx.x;
  int b = i >> 12, n = i & (N_ - 1);
  const float* xb = x + (size_t)b * 3 * N_;
  float x0 = xb[n], x1 = xb[N_ + n], x2 = xb[2 * N_ + n];
  float4 v = make_float4(x0, x1, x2, -0.5f * (x0 * x0 + x1 * x1 + x2 * x2));
  *reinterpret_cast<float4*>(xa0 + (size_t)i * 4) = v;
}

__device__ __forceinline__ float min16f(const float tv[16]) {
  float m0 = fminf(tv[0], tv[1]),   m1 = fminf(tv[2], tv[3]);
  float m2 = fminf(tv[4], tv[5]),   m3 = fminf(tv[6], tv[7]);
  float m4 = fminf(tv[8], tv[9]),   m5 = fminf(tv[10], tv[11]);
  float m6 = fminf(tv[12], tv[13]), m7 = fminf(tv[14], tv[15]);
  return fminf(fminf(fminf(m0, m1), fminf(m2, m3)), fminf(fminf(m4, m5), fminf(m6, m7)));
}

// register-resident top-16 replacement: slot id lives in the 4 low mantissa bits of
// the value, so all 16 packed values are distinct and "find the min entry" is an
// exact equality match; replacement = 16 unrolled compare-selects (no LDS, no scratch).
__device__ __forceinline__ void replace16(float tv[16], int ti[16], float d, int idx,
                                          float& curmin) {
  unsigned mp = __float_as_uint(curmin);
  unsigned s = mp & 15u;
  float dp = __uint_as_float((__float_as_uint(d) & ~15u) | s);
#pragma unroll
  for (int k = 0; k < 16; ++k) {
    bool hit = (__float_as_uint(tv[k]) == mp);
    tv[k] = hit ? dp : tv[k];
    ti[k] = hit ? idx : ti[k];
  }
  curmin = min16f(tv);
}

// ---------------- knn: 1 row per thread scans one 512-candidate chunk ----------------
// key(m) = dot(x_n, x_m) - 0.5*|x_m|^2 (monotone-equivalent to reference pd ranking;
// acc is INITIALIZED from the candidate's -0.5|x_m|^2 column).
// Occupancy-first shape: VGPR<=128 (launch_bounds 256,4), 1024 blocks = 4 blocks/CU,
// LDS 36.9KB*4 = 147KB/CU -> 4 waves/SIMD to hide broadcast-ds_read latency.
template<int CQ>  // feature float4-quads per row: 1 (stride 4) or 9 (stride 36)
__global__ __launch_bounds__(256, 4) void knn_kernel(const float* __restrict__ xa,
                                                     float2* __restrict__ cand16) {
  constexpr int STR = CQ * 4;
  constexpr int NF = (CQ == 1) ? 3 : 32;   // real features; augmented col at NF
  constexpr int TILE = 128;
  constexpr int CHUNK = 4096 / NCH_;
  constexpr int NT = CHUNK / TILE;
  constexpr int TILE_F = TILE * STR;
  constexpr int NPRE = (TILE_F / 4 + 255) / 256;
  __shared__ float tile[2][TILE_F];

  const int b = blockIdx.y;
  const int chunk = blockIdx.x & (NCH_ - 1);
  const int rg = blockIdx.x / NCH_;               // 16 row-groups of 256 rows
  const int row = rg * 256 + threadIdx.x;
  const float* base = xa + (size_t)b * N_ * STR;

  float rf[NF];
  if constexpr (CQ == 1) {
    float4 v = *reinterpret_cast<const float4*>(base + (size_t)row * STR);
    rf[0] = v.x; rf[1] = v.y; rf[2] = v.z;
  } else {
#pragma unroll
    for (int q = 0; q < 8; ++q) {
      float4 v = *reinterpret_cast<const float4*>(base + (size_t)row * STR + 4 * q);
      rf[4 * q] = v.x; rf[4 * q + 1] = v.y; rf[4 * q + 2] = v.z; rf[4 * q + 3] = v.w;
    }
  }

  float tv[16]; int ti[16];
#pragma unroll
  for (int i = 0; i < 16; ++i) {
    tv[i] = __uint_as_float((__float_as_uint(-3.0e38f) & ~15u) | (unsigned)i);
    ti[i] = 0;
  }
  float curmin = min16f(tv);

  const int m0 = chunk * CHUNK;

  // stage tile 0
  {
    const float4* src = reinterpret_cast<const float4*>(base + (size_t)m0 * STR);
    float4* dst = reinterpret_cast<float4*>(tile[0]);
    for (int f = threadIdx.x; f < TILE_F / 4; f += 256) dst[f] = src[f];
  }
  __syncthreads();

  for (int t = 0; t < NT; ++t) {
    const int cur = t & 1;
    float4 pre[NPRE];
    const bool hasNext = (t + 1 < NT);
    if (hasNext) {  // issue next-tile loads early (hide HBM/L2 latency under compute)
      const float4* src = reinterpret_cast<const float4*>(base + (size_t)(m0 + (t + 1) * TILE) * STR);
#pragma unroll
      for (int k = 0; k < NPRE; ++k) {
        int f = threadIdx.x + k * 256;
        if (f < TILE_F / 4) pre[k] = src[f];
      }
    }
    const float* tl = tile[cur];
    for (int mb = 0; mb < TILE; mb += 8) {
      float d[8];
#pragma unroll
      for (int q8 = 0; q8 < 8; ++q8) {
        const float* cf = tl + (mb + q8) * STR;   // uniform address -> broadcast ds_read
        float a;
        if constexpr (CQ == 1) {
          float4 v = *reinterpret_cast<const float4*>(cf);
          a = v.w;                                // -0.5*|x_m|^2 column
          a = fmaf(rf[0], v.x, a);
          a = fmaf(rf[1], v.y, a);
          a = fmaf(rf[2], v.z, a);
        } else {
          a = cf[32];                             // -0.5*|x_m|^2 column (broadcast b32)
#pragma unroll
          for (int q = 0; q < 8; ++q) {
            float4 v = reinterpret_cast<const float4*>(cf)[q];
            a = fmaf(rf[4 * q], v.x, a);
            a = fmaf(rf[4 * q + 1], v.y, a);
            a = fmaf(rf[4 * q + 2], v.z, a);
            a = fmaf(rf[4 * q + 3], v.w, a);
          }
        }
        d[q8] = a;
      }
      float mx = d[0];
#pragma unroll
      for (int q8 = 1; q8 < 8; ++q8) mx = fmaxf(mx, d[q8]);
      const int mbase = m0 + t * TILE + mb;
      if (mx > curmin) {
#pragma unroll
        for (int q8 = 0; q8 < 8; ++q8)
          if (d[q8] > curmin) replace16(tv, ti, d[q8], mbase + q8, curmin);
      }
    }
    if (hasNext) {
      float4* dst = reinterpret_cast<float4*>(tile[cur ^ 1]);
#pragma unroll
      for (int k = 0; k < NPRE; ++k) {
        int f = threadIdx.x + k * 256;
        if (f < TILE_F / 4) dst[f] = pre[k];
      }
    }
    __syncthreads();
  }

  float2* outp = cand16 + ((size_t)(chunk * B_ + b) * N_ + row) * 16;
#pragma unroll
  for (int i = 0; i < 16; ++i)
    outp[i] = make_float2(tv[i], __int_as_float(ti[i]));
}

// ---------------- merge NCH_ chunk-wise top-16 lists -> final idx ----------------
__global__ void knn_merge_kernel(const float2* __restrict__ cand16, int* __restrict__ idx_out) {
  const int i = blockIdx.x * 256 + threadIdx.x;  // row over B*N
  float tv[16]; int ti[16];
  const float2* c0 = cand16 + (size_t)i * 16;
#pragma unroll
  for (int k = 0; k < 16; ++k) { float2 pr = c0[k]; tv[k] = pr.x; ti[k] = __float_as_int(pr.y); }
  float curmin = min16f(tv);
  for (int c = 1; c < NCH_; ++c) {
    const float2* cc = cand16 + ((size_t)c * BN_ + i) * 16;
#pragma unroll
    for (int k = 0; k < 16; ++k) {
      float2 pr = cc[k];
      if (pr.x > curmin) replace16(tv, ti, pr.x, __float_as_int(pr.y), curmin);
    }
  }
  int4* op = reinterpret_cast<int4*>(idx_out + (size_t)i * 16);
  op[0] = make_int4(ti[0], ti[1], ti[2], ti[3]);
  op[1] = make_int4(ti[4], ti[5], ti[6], ti[7]);
  op[2] = make_int4(ti[8], ti[9], ti[10], ti[11]);
  op[3] = make_int4(ti[12], ti[13], ti[14], ti[15]);
}

// ---------------- edge conv: y = W.[center; nb-center]; emit ymax/ymin + BN partials ----
template<int CIN, int O, int ASTR>
__global__ __launch_bounds__(256) void conv_kernel(const float* __restrict__ xa,
                                                   const int* __restrict__ idxg,
                                                   const float* __restrict__ W,
                                                   float* __restrict__ ymax, float* __restrict__ ymin,
                                                   float* __restrict__ partial) {
  constexpr int PPB = 32;                  // points per block
  constexpr int JPL = (O == 64) ? 16 : 8;  // neighbors per lane
  __shared__ float Wt[2 * CIN * O];        // transposed: Wt[c*O+o]
  __shared__ float dbuf[4][CIN * 16];      // per-wave diff tile d[c][j]
  __shared__ float ls1[O], ls2[O];

  const int tid = threadIdx.x;
  const int lane = tid & 63;
  const int wv = tid >> 6;

  for (int i = tid; i < 2 * CIN * O; i += 256) {
    int c = i / O, o2 = i % O;
    Wt[i] = W[o2 * (2 * CIN) + c];
  }
  if (tid < O) { ls1[tid] = 0.f; ls2[tid] = 0.f; }
  __syncthreads();

  const int o = lane % O;
  const int jh = lane / O;
  const int j0 = jh * JPL;
  const int j = lane & 15;
  const int cg = lane >> 4;

  float wreg[CIN];  // diff-part weights, per-lane column
#pragma unroll
  for (int c = 0; c < CIN; ++c) wreg[c] = Wt[(CIN + c) * O + o];

  float s1 = 0.f, s2 = 0.f;
  float* dw = dbuf[wv];

  const int pbase = blockIdx.x * PPB + wv * (PPB / 4);
  for (int p = pbase; p < pbase + PPB / 4; ++p) {
    const int b = p >> 12;
    const float* cp = xa + (size_t)p * ASTR;
    float cf[CIN];
    if constexpr (CIN == 3) {
      float4 v = *reinterpret_cast<const float4*>(cp);
      cf[0] = v.x; cf[1] = v.y; cf[2] = v.z;
    } else {
#pragma unroll
      for (int q = 0; q < CIN / 4; ++q) {
        float4 v = *reinterpret_cast<const float4*>(cp + 4 * q);
        cf[4 * q] = v.x; cf[4 * q + 1] = v.y; cf[4 * q + 2] = v.z; cf[4 * q + 3] = v.w;
      }
    }
    const int idxj = idxg[(size_t)p * 16 + j];
    const float* np = xa + (size_t)(b * N_ + idxj) * ASTR;
    if constexpr (CIN == 3) {
      if (cg == 0) {
        float4 nv = *reinterpret_cast<const float4*>(np);
        dw[0 * 16 + j] = nv.x - cf[0];
        dw[1 * 16 + j] = nv.y - cf[1];
        dw[2 * 16 + j] = nv.z - cf[2];
      }
    } else {
      float4 na = *reinterpret_cast<const float4*>(np + cg * 8);
      float4 nb2 = *reinterpret_cast<const float4*>(np + cg * 8 + 4);
      float4 ca = *reinterpret_cast<const float4*>(cp + cg * 8);
      float4 cb = *reinterpret_cast<const float4*>(cp + cg * 8 + 4);
      dw[(cg * 8 + 0) * 16 + j] = na.x - ca.x;
      dw[(cg * 8 + 1) * 16 + j] = na.y - ca.y;
      dw[(cg * 8 + 2) * 16 + j] = na.z - ca.z;
      dw[(cg * 8 + 3) * 16 + j] = na.w - ca.w;
      dw[(cg * 8 + 4) * 16 + j] = nb2.x - cb.x;
      dw[(cg * 8 + 5) * 16 + j] = nb2.y - cb.y;
      dw[(cg * 8 + 6) * 16 + j] = nb2.z - cb.z;
      dw[(cg * 8 + 7) * 16 + j] = nb2.w - cb.w;
    }
    // center part (k-independent)
    float y0 = 0.f;
#pragma unroll
    for (int c = 0; c < CIN; ++c) y0 = fmaf(Wt[c * O + o], cf[c], y0);
    float y[JPL];
#pragma unroll
    for (int jj = 0; jj < JPL; ++jj) y[jj] = y0;
#pragma unroll
    for (int c = 0; c < CIN; ++c) {
      float w = wreg[c];
#pragma unroll
      for (int jq = 0; jq < JPL / 4; ++jq) {
        float4 d4 = *reinterpret_cast<const float4*>(dw + c * 16 + j0 + 4 * jq);
        y[4 * jq + 0] = fmaf(w, d4.x, y[4 * jq + 0]);
        y[4 * jq + 1] = fmaf(w, d4.y, y[4 * jq + 1]);
        y[4 * jq + 2] = fmaf(w, d4.z, y[4 * jq + 2]);
        y[4 * jq + 3] = fmaf(w, d4.w, y[4 * jq + 3]);
      }
    }
    float mx = y[0], mn = y[0];
#pragma unroll
    for (int jj = 0; jj < JPL; ++jj) {
      s1 += y[jj];
      s2 = fmaf(y[jj], y[jj], s2);
      if (jj) { mx = fmaxf(mx, y[jj]); mn = fminf(mn, y[jj]); }
    }
    if constexpr (O == 32) {
      mx = fmaxf(mx, __shfl_xor(mx, 32));
      mn = fminf(mn, __shfl_xor(mn, 32));
    }
    ymax[(size_t)p * O + o] = mx;
    ymin[(size_t)p * O + o] = mn;
  }
  atomicAdd(&ls1[o], s1);
  atomicAdd(&ls2[o], s2);
  __syncthreads();
  if (tid < O) {
    partial[(size_t)blockIdx.x * (2 * O) + tid] = ls1[tid];
    partial[(size_t)blockIdx.x * (2 * O) + O + tid] = ls2[tid];
  }
}

// ---------------- BN stats -> per-channel affine (a, b) ----------------
template<int O>
__global__ void bnprep_kernel(const float* __restrict__ partial,
                              const float* __restrict__ gamma, const float* __restrict__ beta,
                              float* __restrict__ ab) {
  __shared__ float r1[256], r2[256];
  const int o = blockIdx.x;
  float a1 = 0.f, a2 = 0.f;
  for (int i = threadIdx.x; i < 1024; i += 256) {
    a1 += partial[(size_t)i * (2 * O) + o];
    a2 += partial[(size_t)i * (2 * O) + O + o];
  }
  r1[threadIdx.x] = a1; r2[threadIdx.x] = a2;
  __syncthreads();
  for (int s = 128; s > 0; s >>= 1) {
    if (threadIdx.x < s) { r1[threadIdx.x] += r1[threadIdx.x + s]; r2[threadIdx.x] += r2[threadIdx.x + s]; }
    __syncthreads();
  }
  if (threadIdx.x == 0) {
    const double cnt = (double)BN_ * 16.0;
    double mean = (double)r1[0] / cnt;
    double var = (double)r2[0] / cnt - mean * mean;
    double a = (double)gamma[o] / sqrt(var + (double)BN_EPS);
    ab[o] = (float)a;
    ab[64 + o] = (float)((double)beta[o] - mean * a);
  }
}

// ---------------- finalize: relu(a*(a>0?ymax:ymin)+b), write next xa + global max ----
template<int O, bool WRITE_XA, int GOFF>
__global__ __launch_bounds__(256) void finalize_kernel(const float* __restrict__ ymax,
                                                       const float* __restrict__ ymin,
                                                       const float* __restrict__ ab,
                                                       float* __restrict__ xa_out,
                                                       float* __restrict__ gmax) {
  __shared__ float la[O], lb[O];
  __shared__ unsigned lgm[O];
  const int tid = threadIdx.x;
  if (tid < O) { la[tid] = ab[tid]; lb[tid] = ab[64 + tid]; lgm[tid] = 0u; }
  __syncthreads();
  const int p = blockIdx.x * 256 + tid;
  const int b = p >> 12;
  float sq = 0.f;
#pragma unroll
  for (int q = 0; q < O / 4; ++q) {
    float4 mx = *reinterpret_cast<const float4*>(ymax + (size_t)p * O + 4 * q);
    float4 mn = *reinterpret_cast<const float4*>(ymin + (size_t)p * O + 4 * q);
    float r0, r1, r2, r3;
    { float a = la[4*q+0], c = lb[4*q+0]; r0 = fmaxf(fmaf(a, (a > 0.f ? mx.x : mn.x), c), 0.f); }
    { float a = la[4*q+1], c = lb[4*q+1]; r1 = fmaxf(fmaf(a, (a > 0.f ? mx.y : mn.y), c), 0.f); }
    { float a = la[4*q+2], c = lb[4*q+2]; r2 = fmaxf(fmaf(a, (a > 0.f ? mx.z : mn.z), c), 0.f); }
    { float a = la[4*q+3], c = lb[4*q+3]; r3 = fmaxf(fmaf(a, (a > 0.f ? mx.w : mn.w), c), 0.f); }
    sq = fmaf(r0, r0, sq); sq = fmaf(r1, r1, sq); sq = fmaf(r2, r2, sq); sq = fmaf(r3, r3, sq);
    atomicMax(&lgm[4*q+0], __float_as_uint(r0));
    atomicMax(&lgm[4*q+1], __float_as_uint(r1));
    atomicMax(&lgm[4*q+2], __float_as_uint(r2));
    atomicMax(&lgm[4*q+3], __float_as_uint(r3));
    if constexpr (WRITE_XA)
      *reinterpret_cast<float4*>(xa_out + (size_t)p * 36 + 4 * q) = make_float4(r0, r1, r2, r3);
  }
  if constexpr (WRITE_XA) {
    xa_out[(size_t)p * 36 + 32] = -0.5f * sq;
    xa_out[(size_t)p * 36 + 33] = 0.f;
    xa_out[(size_t)p * 36 + 34] = 0.f;
    xa_out[(size_t)p * 36 + 35] = 0.f;
  }
  __syncthreads();
  if (tid < O)
    atomicMax(reinterpret_cast<unsigned*>(gmax) + b * 128 + GOFF + tid, lgm[tid]);
}

// ---------------- fc: (8,128) @ (64,128)^T + bfc -> (8,64) ----------------
__global__ void fc_kernel(const float* __restrict__ gmax, const float* __restrict__ Wfc,
                          const float* __restrict__ bfc, float* __restrict__ outp) {
  const int t = blockIdx.x * 256 + threadIdx.x;  // 0..511
  const int b = t >> 6, o = t & 63;
  float acc = bfc[o];
  const float* g = gmax + b * 128;
  const float* w = Wfc + o * 128;
#pragma unroll
  for (int c = 0; c < 128; ++c) acc = fmaf(g[c], w[c], acc);
  outp[(size_t)b * 64 + o] = acc;
}

extern "C" void kernel_launch(void* const* d_in, const int* in_sizes, int n_in,
                              void* d_out, int out_size, void* d_ws, size_t ws_size,
                              hipStream_t stream) {
  (void)in_sizes; (void)n_in; (void)out_size; (void)ws_size;
  const float* x   = (const float*)d_in[0];
  const float* W1  = (const float*)d_in[1];
  const float* g1  = (const float*)d_in[2];
  const float* b1  = (const float*)d_in[3];
  const float* W2  = (const float*)d_in[4];
  const float* g2  = (const float*)d_in[5];
  const float* b2  = (const float*)d_in[6];
  const float* W3  = (const float*)d_in[7];
  const float* g3  = (const float*)d_in[8];
  const float* b3  = (const float*)d_in[9];
  const float* Wfc = (const float*)d_in[10];
  const float* bfc = (const float*)d_in[11];
  float* outp = (float*)d_out;

  char* ws = (char*)d_ws;
  size_t off = 0;
  auto alloc = [&](size_t bytes) { char* p = ws + off; off += (bytes + 511) & ~(size_t)511; return p; };
  float* gmax    = (float*)alloc((size_t)B_ * 128 * 4);
  float* ab      = (float*)alloc(128 * 4);
  float* xa0     = (float*)alloc((size_t)BN_ * 4 * 4);
  float* xa1     = (float*)alloc((size_t)BN_ * 36 * 4);
  float* xa2     = (float*)alloc((size_t)BN_ * 36 * 4);
  int*   idxb    = (int*)  alloc((size_t)BN_ * 16 * 4);
  // union region: cand16 (knn+merge phase) aliases {ymax, ymin, partial} (conv phase)
  char*  uni     = alloc((size_t)NCH_ * BN_ * 16 * 8);
  float2* cand16 = (float2*)uni;
  float* ymax    = (float*)uni;
  float* ymin    = (float*)(uni + (size_t)BN_ * 64 * 4);
  float* partial = (float*)(uni + (size_t)BN_ * 64 * 8);

  hipMemsetAsync(gmax, 0, (size_t)B_ * 128 * 4, stream);

  dim3 blk(256);
  prep0_kernel<<<BN_ / 256, blk, 0, stream>>>(x, xa0);

  // layer 1 (C=3 -> 32)
  knn_kernel<1><<<dim3(16 * NCH_, 8), blk, 0, stream>>>(xa0, cand16);
  knn_merge_kernel<<<BN_ / 256, blk, 0, stream>>>(cand16, idxb);
  conv_kernel<3, 32, 4><<<BN_ / 32, blk, 0, stream>>>(xa0, idxb, W1, ymax, ymin, partial);
  bnprep_kernel<32><<<32, blk, 0, stream>>>(partial, g1, b1, ab);
  finalize_kernel<32, true, 0><<<BN_ / 256, blk, 0, stream>>>(ymax, ymin, ab, xa1, gmax);

  // layer 2 (32 -> 32)
  knn_kernel<9><<<dim3(16 * NCH_, 8), blk, 0, stream>>>(xa1, cand16);
  knn_merge_kernel<<<BN_ / 256, blk, 0, stream>>>(cand16, idxb);
  conv_kernel<32, 32, 36><<<BN_ / 32, blk, 0, stream>>>(xa1, idxb, W2, ymax, ymin, partial);
  bnprep_kernel<32><<<32, blk, 0, stream>>>(partial, g2, b2, ab);
  finalize_kernel<32, true, 32><<<BN_ / 256, blk, 0, stream>>>(ymax, ymin, ab, xa2, gmax);

  // layer 3 (32 -> 64)
  knn_kernel<9><<<dim3(16 * NCH_, 8), blk, 0, stream>>>(xa2, cand16);
  knn_merge_kernel<<<BN_ / 256, blk, 0, stream>>>(cand16, idxb);
  conv_kernel<32, 64, 36><<<BN_ / 32, blk, 0, stream>>>(xa2, idxb, W3, ymax, ymin, partial);
  bnprep_kernel<64><<<64, blk, 0, stream>>>(partial, g3, b3, ab);
  finalize_kernel<64, false, 64><<<BN_ / 256, blk, 0, stream>>>(ymax, ymin, ab, nullptr, gmax);

  fc_kernel<<<2, blk, 0, stream>>>(gmax, Wfc, bfc, outp);
}